// Round 1
// baseline (1238.154 us; speedup 1.0000x reference)
//
#include <hip/hip_runtime.h>
#include <hip/hip_bf16.h>
#include <math.h>

#define FDIM 512
#define MFD  4096
#define CNUM 20
#define BATCH 2048
#define SMAX 256   // max rows per class (true counts ~102 +/- 10, hard bound)

__device__ inline float dot4acc(float4 a, float4 b, float acc) {
  acc = fmaf(a.x, b.x, acc); acc = fmaf(a.y, b.y, acc);
  acc = fmaf(a.z, b.z, acc); acc = fmaf(a.w, b.w, acc);
  return acc;
}

// ---------------- generic tiled GEMM: C = act(A @ B^T + bias) ----------------
// A:[M,K] row-major, B:[N,K] row-major (i.e. torch Linear weight), C:[M,N].
// Requires M,N % 64 == 0, K % 32 == 0.  ACT: 0=none 1=relu 2=tanh
template<int ACT>
__global__ __launch_bounds__(256) void gemm_nt(const float* __restrict__ A,
                                               const float* __restrict__ B,
                                               const float* __restrict__ bias,
                                               float* __restrict__ C,
                                               int M, int N, int K) {
  __shared__ float As[32][68];   // [k][m], pad 68 -> 16B-aligned rows for b128 reads
  __shared__ float Bs[32][68];
  const int t  = threadIdx.x;
  const int m0 = blockIdx.y * 64;
  const int n0 = blockIdx.x * 64;
  const int tx = t & 15, ty = t >> 4;    // 16x16 threads, each 4x4 outputs
  const int lk = t & 31, lr = t >> 5;    // staging: lane over k, 8 rows/pass
  float acc[4][4] = {};
  for (int k0 = 0; k0 < K; k0 += 32) {
#pragma unroll
    for (int p = 0; p < 8; ++p) {
      int row = lr + p * 8;
      As[lk][row] = A[(size_t)(m0 + row) * K + k0 + lk];
      Bs[lk][row] = B[(size_t)(n0 + row) * K + k0 + lk];
    }
    __syncthreads();
#pragma unroll
    for (int kk = 0; kk < 32; ++kk) {
      float4 a = *(const float4*)&As[kk][ty * 4];
      float4 b = *(const float4*)&Bs[kk][tx * 4];
      float va[4] = {a.x, a.y, a.z, a.w};
      float vb[4] = {b.x, b.y, b.z, b.w};
#pragma unroll
      for (int i = 0; i < 4; ++i)
#pragma unroll
        for (int j = 0; j < 4; ++j) acc[i][j] = fmaf(va[i], vb[j], acc[i][j]);
    }
    __syncthreads();
  }
#pragma unroll
  for (int i = 0; i < 4; ++i) {
    float r[4];
#pragma unroll
    for (int j = 0; j < 4; ++j) {
      float v = acc[i][j] + bias[n0 + tx * 4 + j];
      if (ACT == 1) v = fmaxf(v, 0.f);
      if (ACT == 2) v = tanhf(v);
      r[j] = v;
    }
    *(float4*)&C[(size_t)(m0 + ty * 4 + i) * N + n0 + tx * 4] =
        make_float4(r[0], r[1], r[2], r[3]);
  }
}

// ---------------- per-class index lists ----------------
__global__ void build_idx(const int* __restrict__ label, int* __restrict__ idx,
                          int* __restrict__ counts) {
  __shared__ int cnt[CNUM];
  int t = threadIdx.x;
  if (t < CNUM) cnt[t] = 0;
  __syncthreads();
  for (int b = t; b < BATCH; b += 256) {
    int c = label[b];
    int p = atomicAdd(&cnt[c], 1);
    idx[c * BATCH + p] = b;
  }
  __syncthreads();
  if (t < CNUM) counts[t] = cnt[t];
}

// ---------------- per-class gram: S_c = G_c @ G_c^T (gathered rows) ----------------
__global__ __launch_bounds__(256) void gram_cls(const float* __restrict__ G,
                                                const int* __restrict__ idx,
                                                const int* __restrict__ counts,
                                                float* __restrict__ S) {
  const int c = blockIdx.z;
  const int n = counts[c];
  const int i0 = blockIdx.y * 32, j0 = blockIdx.x * 32;
  if (i0 >= n || j0 >= n) return;
  const int* idc = idx + c * BATCH;
  __shared__ float As[32][36];
  __shared__ float Bs[32][36];
  const int t = threadIdx.x;
  const int tx = t & 15, ty = t >> 4;   // each thread 2x2 of the 32x32 tile
  const int lk = t & 31, lr = t >> 5;
  int gi[4], gj[4];
#pragma unroll
  for (int p = 0; p < 4; ++p) {
    int r = lr + p * 8;
    int ri = i0 + r, rj = j0 + r;
    gi[p] = idc[ri < n ? ri : 0];
    gj[p] = idc[rj < n ? rj : 0];
  }
  float acc[2][2] = {};
  for (int k0 = 0; k0 < MFD; k0 += 32) {
#pragma unroll
    for (int p = 0; p < 4; ++p) {
      int r = lr + p * 8;
      As[lk][r] = G[(size_t)gi[p] * MFD + k0 + lk];
      Bs[lk][r] = G[(size_t)gj[p] * MFD + k0 + lk];
    }
    __syncthreads();
#pragma unroll
    for (int kk = 0; kk < 32; ++kk) {
      float2 a = *(const float2*)&As[kk][ty * 2];
      float2 b = *(const float2*)&Bs[kk][tx * 2];
      acc[0][0] = fmaf(a.x, b.x, acc[0][0]);
      acc[0][1] = fmaf(a.x, b.y, acc[0][1]);
      acc[1][0] = fmaf(a.y, b.x, acc[1][0]);
      acc[1][1] = fmaf(a.y, b.y, acc[1][1]);
    }
    __syncthreads();
  }
  float* Sc = S + (size_t)c * SMAX * SMAX;
#pragma unroll
  for (int i = 0; i < 2; ++i)
#pragma unroll
    for (int j = 0; j < 2; ++j)
      Sc[(size_t)(i0 + ty * 2 + i) * SMAX + (j0 + tx * 2 + j)] = acc[i][j];
}

// ---------- per-class: row softmax of S, accumulate column weights w_j = sum_i A[i,j] ----------
__global__ __launch_bounds__(256) void softmax_w(const float* __restrict__ S,
                                                 const int* __restrict__ counts,
                                                 float* __restrict__ W) {
  const int c = blockIdx.x;
  const int n = counts[c];
  __shared__ float wacc[4][SMAX];
  const int t = threadIdx.x, lane = t & 63, wid = t >> 6;
  for (int j = t; j < 4 * SMAX; j += 256) (&wacc[0][0])[j] = 0.f;
  __syncthreads();
  const float* Sc = S + (size_t)c * SMAX * SMAX;
  for (int i = wid; i < n; i += 4) {          // one row per wave
    const float* row = Sc + (size_t)i * SMAX;
    float v[4];
    float m = -INFINITY;
#pragma unroll
    for (int q = 0; q < 4; ++q) {
      int j = lane + q * 64;
      v[q] = (j < n) ? row[j] : -INFINITY;
      m = fmaxf(m, v[q]);
    }
#pragma unroll
    for (int s = 32; s; s >>= 1) m = fmaxf(m, __shfl_xor(m, s));
    float e[4], sum = 0.f;
#pragma unroll
    for (int q = 0; q < 4; ++q) {
      int j = lane + q * 64;
      e[q] = (j < n) ? expf(v[q] - m) : 0.f;
      sum += e[q];
    }
#pragma unroll
    for (int s = 32; s; s >>= 1) sum += __shfl_xor(sum, s);
    float inv = 1.f / sum;
#pragma unroll
    for (int q = 0; q < 4; ++q) {
      int j = lane + q * 64;
      if (j < n) wacc[wid][j] += e[q] * inv;
    }
  }
  __syncthreads();
  for (int j = t; j < SMAX; j += 256)
    W[c * SMAX + j] = wacc[0][j] + wacc[1][j] + wacc[2][j] + wacc[3][j];
}

// ---------- attn_labels[c,:] = (1/n_c) * sum_j w_j * label0[idx_c[j], :] ----------
__global__ __launch_bounds__(256) void attn_combine(const float* __restrict__ G,
                                                    const int* __restrict__ idx,
                                                    const int* __restrict__ counts,
                                                    const float* __restrict__ W,
                                                    float* __restrict__ attn) {
  const int c = blockIdx.y;
  const int col = blockIdx.x * 256 + threadIdx.x;
  const int n = counts[c];
  const int* idc = idx + c * BATCH;
  float acc = 0.f;
#pragma unroll 4
  for (int j = 0; j < n; ++j)
    acc = fmaf(W[c * SMAX + j], G[(size_t)idc[j] * MFD + col], acc);
  attn[(size_t)c * MFD + col] = (n > 0) ? acc / (float)n : 0.f;
}

// ---------- hs = select(sigmoid(attn@W7^T + b7 + hs_init@W8^T + b8), hs_init) ----------
// grid = MFD/16 blocks; each wave owns 4 output cols o, all 20 classes.
__global__ __launch_bounds__(256) void skinny_hs(const float* __restrict__ attn,
                                                 const float* __restrict__ hsin,
                                                 const float* __restrict__ W7,
                                                 const float* __restrict__ b7,
                                                 const float* __restrict__ W8,
                                                 const float* __restrict__ b8,
                                                 const int* __restrict__ counts,
                                                 float* __restrict__ hs) {
  const int t = threadIdx.x, lane = t & 63, wid = t >> 6;
  const int o0 = blockIdx.x * 16 + wid * 4;
  const float4* A4 = (const float4*)attn;
  const float4* H4 = (const float4*)hsin;
  float acc[CNUM][4] = {};
  for (int i = 0; i < MFD / 4 / 64; ++i) {
    int k4 = lane + i * 64;
    float4 w7v[4], w8v[4];
#pragma unroll
    for (int o = 0; o < 4; ++o) {
      w7v[o] = *((const float4*)(W7 + (size_t)(o0 + o) * MFD) + k4);
      w8v[o] = *((const float4*)(W8 + (size_t)(o0 + o) * MFD) + k4);
    }
#pragma unroll
    for (int c = 0; c < CNUM; ++c) {
      float4 av = A4[(size_t)c * (MFD / 4) + k4];
      float4 hv = H4[(size_t)c * (MFD / 4) + k4];
#pragma unroll
      for (int o = 0; o < 4; ++o)
        acc[c][o] = dot4acc(hv, w8v[o], dot4acc(av, w7v[o], acc[c][o]));
    }
  }
#pragma unroll
  for (int c = 0; c < CNUM; ++c)
#pragma unroll
    for (int o = 0; o < 4; ++o)
#pragma unroll
      for (int s = 32; s; s >>= 1) acc[c][o] += __shfl_xor(acc[c][o], s);
  if (lane == 0) {
#pragma unroll
    for (int c = 0; c < CNUM; ++c) {
      bool ne = counts[c] > 0;
#pragma unroll
      for (int o = 0; o < 4; ++o) {
        int oo = o0 + o;
        float v = acc[c][o] + b7[oo] + b8[oo];
        v = 1.f / (1.f + expf(-v));
        hs[(size_t)c * MFD + oo] = ne ? v : hsin[(size_t)c * MFD + oo];
      }
    }
  }
}

// ---------- labels = select(tanh(hs@W9^T + b9), labels_init) ----------
__global__ __launch_bounds__(256) void skinny_lab(const float* __restrict__ hsv,
                                                  const float* __restrict__ W9,
                                                  const float* __restrict__ b9,
                                                  const int* __restrict__ counts,
                                                  const float* __restrict__ labinit,
                                                  float* __restrict__ labels) {
  const int t = threadIdx.x, lane = t & 63, wid = t >> 6;
  const int o0 = blockIdx.x * 16 + wid * 4;
  const float4* H4 = (const float4*)hsv;
  float acc[CNUM][4] = {};
  for (int i = 0; i < MFD / 4 / 64; ++i) {
    int k4 = lane + i * 64;
    float4 w9v[4];
#pragma unroll
    for (int o = 0; o < 4; ++o)
      w9v[o] = *((const float4*)(W9 + (size_t)(o0 + o) * MFD) + k4);
#pragma unroll
    for (int c = 0; c < CNUM; ++c) {
      float4 hv = H4[(size_t)c * (MFD / 4) + k4];
#pragma unroll
      for (int o = 0; o < 4; ++o) acc[c][o] = dot4acc(hv, w9v[o], acc[c][o]);
    }
  }
#pragma unroll
  for (int c = 0; c < CNUM; ++c)
#pragma unroll
    for (int o = 0; o < 4; ++o)
#pragma unroll
      for (int s = 32; s; s >>= 1) acc[c][o] += __shfl_xor(acc[c][o], s);
  if (lane == 0) {
#pragma unroll
    for (int c = 0; c < CNUM; ++c) {
      bool ne = counts[c] > 0;
#pragma unroll
      for (int o = 0; o < 4; ++o) {
        int oo = o0 + o;
        float v = tanhf(acc[c][o] + b9[oo]);
        labels[(size_t)c * MFD + oo] = ne ? v : labinit[(size_t)c * MFD + oo];
      }
    }
  }
}

// ---------- row L2 norms ----------
__global__ __launch_bounds__(256) void rownorm(const float* __restrict__ X,
                                               float* __restrict__ out, int ncols) {
  const int b = blockIdx.x, t = threadIdx.x;
  const float4* X4 = (const float4*)(X + (size_t)b * ncols);
  float ss = 0.f;
  for (int i = t; i < ncols / 4; i += 256) {
    float4 v = X4[i];
    ss = dot4acc(v, v, ss);
  }
#pragma unroll
  for (int s = 32; s; s >>= 1) ss += __shfl_xor(ss, s);
  __shared__ float red[4];
  const int lane = t & 63, wid = t >> 6;
  if (lane == 0) red[wid] = ss;
  __syncthreads();
  if (t == 0) out[b] = sqrtf(red[0] + red[1] + red[2] + red[3]);
}

// ---------- outs[b,c] = (out_b . labels_c) / max(|out_b||labels_c|, 1e-8) ----------
__global__ __launch_bounds__(256) void outs_kernel(const float* __restrict__ outb,
                                                   const float* __restrict__ labels,
                                                   const float* __restrict__ no,
                                                   const float* __restrict__ nl,
                                                   float* __restrict__ dout) {
  const int b = blockIdx.x, t = threadIdx.x;
  const float4* O4 = (const float4*)(outb + (size_t)b * MFD);
  const float4* L4 = (const float4*)labels;
  float acc[CNUM] = {};
  for (int i = t; i < MFD / 4; i += 256) {
    float4 ov = O4[i];
#pragma unroll
    for (int c = 0; c < CNUM; ++c)
      acc[c] = dot4acc(ov, L4[(size_t)c * (MFD / 4) + i], acc[c]);
  }
#pragma unroll
  for (int c = 0; c < CNUM; ++c)
#pragma unroll
    for (int s = 32; s; s >>= 1) acc[c] += __shfl_xor(acc[c], s);
  __shared__ float red[4][CNUM];
  const int lane = t & 63, wid = t >> 6;
  if (lane == 0) {
#pragma unroll
    for (int c = 0; c < CNUM; ++c) red[wid][c] = acc[c];
  }
  __syncthreads();
  if (t < CNUM) {
    float v = red[0][t] + red[1][t] + red[2][t] + red[3][t];
    float d = fmaxf(no[b] * nl[t], 1e-8f);
    dout[(size_t)b * CNUM + t] = v / d;
  }
}

// ---------- ls[c1,c2] = tanh(labels_c1 . W5_c2 + b5_c2)  -> rows BATCH..BATCH+C ----------
__global__ __launch_bounds__(256) void ls_kernel(const float* __restrict__ labels,
                                                 const float* __restrict__ W5,
                                                 const float* __restrict__ b5,
                                                 float* __restrict__ dout) {
  const int c1 = blockIdx.x, t = threadIdx.x;
  __shared__ float lrow[MFD];
  for (int i = t; i < MFD; i += 256) lrow[i] = labels[(size_t)c1 * MFD + i];
  __syncthreads();
  const int lane = t & 63, wid = t >> 6;
  for (int c2 = wid; c2 < CNUM; c2 += 4) {
    const float4* w = (const float4*)(W5 + (size_t)c2 * MFD);
    float acc = 0.f;
    for (int i = lane; i < MFD / 4; i += 64)
      acc = dot4acc(*(const float4*)&lrow[i * 4], w[i], acc);
#pragma unroll
    for (int s = 32; s; s >>= 1) acc += __shfl_xor(acc, s);
    if (lane == 0)
      dout[(size_t)(BATCH + c1) * CNUM + c2] = tanhf(acc + b5[c2]);
  }
}

extern "C" void kernel_launch(void* const* d_in, const int* in_sizes, int n_in,
                              void* d_out, int out_size, void* d_ws, size_t ws_size,
                              hipStream_t stream) {
  const float* x    = (const float*)d_in[0];
  const int*   lab  = (const int*)d_in[1];
  const float* W1 = (const float*)d_in[2];  const float* b1 = (const float*)d_in[3];
  const float* W2 = (const float*)d_in[4];  const float* b2 = (const float*)d_in[5];
  const float* W3 = (const float*)d_in[6];  const float* b3 = (const float*)d_in[7];
  const float* W4 = (const float*)d_in[8];  const float* b4 = (const float*)d_in[9];
  const float* W5 = (const float*)d_in[10]; const float* b5 = (const float*)d_in[11];
  const float* W7 = (const float*)d_in[12]; const float* b7 = (const float*)d_in[13];
  const float* W8 = (const float*)d_in[14]; const float* b8 = (const float*)d_in[15];
  const float* W9 = (const float*)d_in[16]; const float* b9 = (const float*)d_in[17];
  const float* hs_init  = (const float*)d_in[18];
  const float* lab_init = (const float*)d_in[19];
  float* out = (float*)d_out;

  float* ws = (float*)d_ws;
  size_t off = 0;
  float* h1     = ws + off; off += (size_t)BATCH * FDIM;
  float* h2     = ws + off; off += (size_t)BATCH * FDIM;
  float* label0 = ws + off; off += (size_t)BATCH * MFD;
  float* outb   = ws + off; off += (size_t)BATCH * MFD;
  float* S      = ws + off; off += (size_t)CNUM * SMAX * SMAX;
  float* wsum   = ws + off; off += (size_t)CNUM * SMAX;
  float* attn   = ws + off; off += (size_t)CNUM * MFD;
  float* hsbuf  = ws + off; off += (size_t)CNUM * MFD;
  float* labels = ws + off; off += (size_t)CNUM * MFD;
  float* no     = ws + off; off += BATCH;
  float* nl     = ws + off; off += 64;
  int* idx      = (int*)(ws + off); off += (size_t)CNUM * BATCH;
  int* counts   = (int*)(ws + off); off += 64;

  gemm_nt<1><<<dim3(FDIM / 64, BATCH / 64), 256, 0, stream>>>(x,  W1, b1, h1, BATCH, FDIM, FDIM);
  gemm_nt<1><<<dim3(FDIM / 64, BATCH / 64), 256, 0, stream>>>(h1, W2, b2, h2, BATCH, FDIM, FDIM);
  gemm_nt<2><<<dim3(MFD / 64, BATCH / 64), 256, 0, stream>>>(h2, W3, b3, label0, BATCH, MFD, FDIM);
  gemm_nt<2><<<dim3(MFD / 64, BATCH / 64), 256, 0, stream>>>(h2, W4, b4, outb,   BATCH, MFD, FDIM);
  build_idx<<<1, 256, 0, stream>>>(lab, idx, counts);
  gram_cls<<<dim3(SMAX / 32, SMAX / 32, CNUM), 256, 0, stream>>>(label0, idx, counts, S);
  softmax_w<<<CNUM, 256, 0, stream>>>(S, counts, wsum);
  attn_combine<<<dim3(MFD / 256, CNUM), 256, 0, stream>>>(label0, idx, counts, wsum, attn);
  skinny_hs<<<MFD / 16, 256, 0, stream>>>(attn, hs_init, W7, b7, W8, b8, counts, hsbuf);
  skinny_lab<<<MFD / 16, 256, 0, stream>>>(hsbuf, W9, b9, counts, lab_init, labels);
  rownorm<<<BATCH, 256, 0, stream>>>(outb, no, MFD);
  rownorm<<<CNUM, 256, 0, stream>>>(labels, nl, MFD);
  outs_kernel<<<BATCH, 256, 0, stream>>>(outb, labels, no, nl, out);
  ls_kernel<<<CNUM, 256, 0, stream>>>(labels, W5, b5, out);
}

// Round 3
// 781.534 us; speedup vs baseline: 1.5843x; 1.5843x over previous
//
#include <hip/hip_runtime.h>
#include <hip/hip_bf16.h>
#include <math.h>

#define FDIM 512
#define MFD  4096
#define CNUM 20
#define BATCH 2048
#define SMAX 256
#define KSPLIT 8

typedef __attribute__((ext_vector_type(8))) short bf16x8;
typedef __attribute__((ext_vector_type(4))) float f32x4;

__device__ inline unsigned short f2bf1(float f) {
  union { float f; unsigned u; } a; a.f = f;
  unsigned r = a.u + 0x7fffu + ((a.u >> 16) & 1u);   // RNE
  return (unsigned short)(r >> 16);
}

__device__ inline float dot4acc(float4 a, float4 b, float acc) {
  acc = fmaf(a.x, b.x, acc); acc = fmaf(a.y, b.y, acc);
  acc = fmaf(a.z, b.z, acc); acc = fmaf(a.w, b.w, acc);
  return acc;
}

__device__ inline void gload_lds16(const void* g, void* l) {
  __builtin_amdgcn_global_load_lds(
      (const __attribute__((address_space(1))) unsigned int*)g,
      (__attribute__((address_space(3))) unsigned int*)l, 16, 0, 0);
}

// ---------------- fp32 -> bf16 conversion (vectorized) ----------------
__global__ __launch_bounds__(256) void cvt_bf16(const float* __restrict__ in,
                                                unsigned short* __restrict__ out, int n4) {
  int i = blockIdx.x * 256 + threadIdx.x;
  if (i >= n4) return;
  float4 v = ((const float4*)in)[i];
  ushort4 o = make_ushort4(f2bf1(v.x), f2bf1(v.y), f2bf1(v.z), f2bf1(v.w));
  ((ushort4*)out)[i] = o;
}

// ---------------- bf16 MFMA GEMM: C = act(A @ B^T + bias) ----------------
// A:[M,K] bf16 row-major, B:[N,K] bf16 row-major. 128x128 tile, BK=32, 4 waves.
// LDS: A-tile [128][32] bf16 (8KB) + B-tile (8KB), XOR-swizzled 16B slots:
//   byte(r, q) = r*64 + (q ^ ((r>>1)&3))*16  -> 16-lane frag reads are 2-way (free).
// ACT: 0=none 1=relu 2=tanh.  OUTBF: store bf16 (Cb) else fp32 (Cf).
template<int ACT, int OUTBF>
__global__ __launch_bounds__(256) void mfma_gemm(const unsigned short* __restrict__ A,
                                                 const unsigned short* __restrict__ B,
                                                 const float* __restrict__ bias,
                                                 float* __restrict__ Cf,
                                                 unsigned short* __restrict__ Cb,
                                                 int M, int N, int K) {
  __shared__ __align__(16) char lds[16384];
  const int t = threadIdx.x, lane = t & 63, w = t >> 6;
  const int wr = w >> 1, wc = w & 1;
  const int m0 = blockIdx.y * 128, n0 = blockIdx.x * 128;

  f32x4 acc[4][4];
#pragma unroll
  for (int m = 0; m < 4; ++m)
#pragma unroll
    for (int n = 0; n < 4; ++n) acc[m][n] = (f32x4){0.f, 0.f, 0.f, 0.f};

  // per-issue staging geometry (2 issues per wave per matrix, 1KB each)
  int rS[2], qS[2];
#pragma unroll
  for (int i = 0; i < 2; ++i) {
    int t16 = (w * 2 + i) * 64 + lane;
    rS[i] = t16 >> 2;
    qS[i] = (t16 & 3) ^ ((rS[i] >> 1) & 3);
  }

  for (int k0 = 0; k0 < K; k0 += 32) {
#pragma unroll
    for (int i = 0; i < 2; ++i) {
      gload_lds16(A + (size_t)(m0 + rS[i]) * K + k0 + qS[i] * 8,
                  lds + (w * 2 + i) * 1024);
      gload_lds16(B + (size_t)(n0 + rS[i]) * K + k0 + qS[i] * 8,
                  lds + 8192 + (w * 2 + i) * 1024);
    }
    __syncthreads();   // drains vmcnt (global_load_lds) then barrier

    bf16x8 af[4], bfr[4];
    const int kq = lane >> 4, l15 = lane & 15;
#pragma unroll
    for (int m = 0; m < 4; ++m) {
      int ra = wr * 64 + m * 16 + l15;
      af[m] = *(const bf16x8*)(lds + ra * 64 + ((kq ^ ((ra >> 1) & 3)) << 4));
      int rb = wc * 64 + m * 16 + l15;
      bfr[m] = *(const bf16x8*)(lds + 8192 + rb * 64 + ((kq ^ ((rb >> 1) & 3)) << 4));
    }
#pragma unroll
    for (int m = 0; m < 4; ++m)
#pragma unroll
      for (int n = 0; n < 4; ++n)
        acc[m][n] = __builtin_amdgcn_mfma_f32_16x16x32_bf16(af[m], bfr[n], acc[m][n], 0, 0, 0);
    __syncthreads();
  }

  // epilogue: C/D layout col = lane&15, row = (lane>>4)*4 + j   [m89-verified]
#pragma unroll
  for (int n = 0; n < 4; ++n) {
    int col = n0 + wc * 64 + n * 16 + (lane & 15);
    float bv = bias[col];
#pragma unroll
    for (int m = 0; m < 4; ++m) {
      int rbase = m0 + wr * 64 + m * 16 + ((lane >> 4) << 2);
#pragma unroll
      for (int j = 0; j < 4; ++j) {
        float v = acc[m][n][j] + bv;
        if (ACT == 1) v = fmaxf(v, 0.f);
        if (ACT == 2) v = tanhf(v);
        if (OUTBF) Cb[(size_t)(rbase + j) * N + col] = f2bf1(v);
        else       Cf[(size_t)(rbase + j) * N + col] = v;
      }
    }
  }
}

// ---------------- per-class index lists ----------------
__global__ void build_idx(const int* __restrict__ label, int* __restrict__ idx,
                          int* __restrict__ counts) {
  __shared__ int cnt[CNUM];
  int t = threadIdx.x;
  if (t < CNUM) cnt[t] = 0;
  __syncthreads();
  for (int b = t; b < BATCH; b += 256) {
    int c = label[b];
    int p = atomicAdd(&cnt[c], 1);
    idx[c * BATCH + p] = b;
  }
  __syncthreads();
  if (t < CNUM) counts[t] = cnt[t];
}

// -------- per-class gram, split-K x8 with atomic accumulation (S pre-zeroed) --------
__global__ __launch_bounds__(256) void gram_splitk(const float* __restrict__ G,
                                                   const int* __restrict__ idx,
                                                   const int* __restrict__ counts,
                                                   float* __restrict__ S) {
  const int z = blockIdx.z, c = z / KSPLIT, ks = z % KSPLIT;
  const int n = counts[c];
  const int i0 = blockIdx.y * 32, j0 = blockIdx.x * 32;
  if (i0 >= n || j0 >= n) return;
  const int* idc = idx + c * BATCH;
  __shared__ float As[32][36];
  __shared__ float Bs[32][36];
  const int t = threadIdx.x;
  const int tx = t & 15, ty = t >> 4;
  const int lk = t & 31, lr = t >> 5;
  int gi[4], gj[4];
#pragma unroll
  for (int p = 0; p < 4; ++p) {
    int r = lr + p * 8;
    int ri = i0 + r, rj = j0 + r;
    gi[p] = idc[ri < n ? ri : 0];
    gj[p] = idc[rj < n ? rj : 0];
  }
  const int kbeg = ks * (MFD / KSPLIT), kend = kbeg + MFD / KSPLIT;
  float acc[2][2] = {};
  for (int k0 = kbeg; k0 < kend; k0 += 32) {
#pragma unroll
    for (int p = 0; p < 4; ++p) {
      int r = lr + p * 8;
      As[lk][r] = G[(size_t)gi[p] * MFD + k0 + lk];
      Bs[lk][r] = G[(size_t)gj[p] * MFD + k0 + lk];
    }
    __syncthreads();
#pragma unroll
    for (int kk = 0; kk < 32; ++kk) {
      float2 a = *(const float2*)&As[kk][ty * 2];
      float2 b = *(const float2*)&Bs[kk][tx * 2];
      acc[0][0] = fmaf(a.x, b.x, acc[0][0]);
      acc[0][1] = fmaf(a.x, b.y, acc[0][1]);
      acc[1][0] = fmaf(a.y, b.x, acc[1][0]);
      acc[1][1] = fmaf(a.y, b.y, acc[1][1]);
    }
    __syncthreads();
  }
  float* Sc = S + (size_t)c * SMAX * SMAX;
#pragma unroll
  for (int i = 0; i < 2; ++i)
#pragma unroll
    for (int j = 0; j < 2; ++j)
      atomicAdd(&Sc[(size_t)(i0 + ty * 2 + i) * SMAX + (j0 + tx * 2 + j)], acc[i][j]);
}

// ---------- per-class: row softmax of S, accumulate column weights ----------
__global__ __launch_bounds__(256) void softmax_w(const float* __restrict__ S,
                                                 const int* __restrict__ counts,
                                                 float* __restrict__ W) {
  const int c = blockIdx.x;
  const int n = counts[c];
  __shared__ float wacc[4][SMAX];
  const int t = threadIdx.x, lane = t & 63, wid = t >> 6;
  for (int j = t; j < 4 * SMAX; j += 256) (&wacc[0][0])[j] = 0.f;
  __syncthreads();
  const float* Sc = S + (size_t)c * SMAX * SMAX;
  for (int i = wid; i < n; i += 4) {
    const float* row = Sc + (size_t)i * SMAX;
    float v[4];
    float m = -INFINITY;
#pragma unroll
    for (int q = 0; q < 4; ++q) {
      int j = lane + q * 64;
      v[q] = (j < n) ? row[j] : -INFINITY;
      m = fmaxf(m, v[q]);
    }
#pragma unroll
    for (int s = 32; s; s >>= 1) m = fmaxf(m, __shfl_xor(m, s));
    float e[4], sum = 0.f;
#pragma unroll
    for (int q = 0; q < 4; ++q) {
      int j = lane + q * 64;
      e[q] = (j < n) ? expf(v[q] - m) : 0.f;
      sum += e[q];
    }
#pragma unroll
    for (int s = 32; s; s >>= 1) sum += __shfl_xor(sum, s);
    float inv = 1.f / sum;
#pragma unroll
    for (int q = 0; q < 4; ++q) {
      int j = lane + q * 64;
      if (j < n) wacc[wid][j] += e[q] * inv;
    }
  }
  __syncthreads();
  for (int j = t; j < SMAX; j += 256)
    W[c * SMAX + j] = wacc[0][j] + wacc[1][j] + wacc[2][j] + wacc[3][j];
}

// ---------- attn_labels[c,:] = (1/n_c) * sum_j w_j * label0[idx_c[j], :] ----------
__global__ __launch_bounds__(256) void attn_combine(const float* __restrict__ G,
                                                    const int* __restrict__ idx,
                                                    const int* __restrict__ counts,
                                                    const float* __restrict__ W,
                                                    float* __restrict__ attn) {
  const int c = blockIdx.y;
  const int col = blockIdx.x * 256 + threadIdx.x;
  const int n = counts[c];
  const int* idc = idx + c * BATCH;
  float acc = 0.f;
#pragma unroll 4
  for (int j = 0; j < n; ++j)
    acc = fmaf(W[c * SMAX + j], G[(size_t)idc[j] * MFD + col], acc);
  attn[(size_t)c * MFD + col] = (n > 0) ? acc / (float)n : 0.f;
}

// ---------- hs = select(sigmoid(attn@W7^T + b7 + hs_init@W8^T + b8), hs_init) ----------
__global__ __launch_bounds__(256) void skinny_hs(const float* __restrict__ attn,
                                                 const float* __restrict__ hsin,
                                                 const float* __restrict__ W7,
                                                 const float* __restrict__ b7,
                                                 const float* __restrict__ W8,
                                                 const float* __restrict__ b8,
                                                 const int* __restrict__ counts,
                                                 float* __restrict__ hs) {
  const int t = threadIdx.x, lane = t & 63, wid = t >> 6;
  const int o0 = blockIdx.x * 16 + wid * 4;
  const float4* A4 = (const float4*)attn;
  const float4* H4 = (const float4*)hsin;
  float acc[CNUM][4] = {};
  for (int i = 0; i < MFD / 4 / 64; ++i) {
    int k4 = lane + i * 64;
    float4 w7v[4], w8v[4];
#pragma unroll
    for (int o = 0; o < 4; ++o) {
      w7v[o] = *((const float4*)(W7 + (size_t)(o0 + o) * MFD) + k4);
      w8v[o] = *((const float4*)(W8 + (size_t)(o0 + o) * MFD) + k4);
    }
#pragma unroll
    for (int c = 0; c < CNUM; ++c) {
      float4 av = A4[(size_t)c * (MFD / 4) + k4];
      float4 hv = H4[(size_t)c * (MFD / 4) + k4];
#pragma unroll
      for (int o = 0; o < 4; ++o)
        acc[c][o] = dot4acc(hv, w8v[o], dot4acc(av, w7v[o], acc[c][o]));
    }
  }
#pragma unroll
  for (int c = 0; c < CNUM; ++c)
#pragma unroll
    for (int o = 0; o < 4; ++o)
#pragma unroll
      for (int s = 32; s; s >>= 1) acc[c][o] += __shfl_xor(acc[c][o], s);
  if (lane == 0) {
#pragma unroll
    for (int c = 0; c < CNUM; ++c) {
      bool ne = counts[c] > 0;
#pragma unroll
      for (int o = 0; o < 4; ++o) {
        int oo = o0 + o;
        float v = acc[c][o] + b7[oo] + b8[oo];
        v = 1.f / (1.f + expf(-v));
        hs[(size_t)c * MFD + oo] = ne ? v : hsin[(size_t)c * MFD + oo];
      }
    }
  }
}

// ---------- labels = select(tanh(hs@W9^T + b9), labels_init) ----------
__global__ __launch_bounds__(256) void skinny_lab(const float* __restrict__ hsv,
                                                  const float* __restrict__ W9,
                                                  const float* __restrict__ b9,
                                                  const int* __restrict__ counts,
                                                  const float* __restrict__ labinit,
                                                  float* __restrict__ labels) {
  const int t = threadIdx.x, lane = t & 63, wid = t >> 6;
  const int o0 = blockIdx.x * 16 + wid * 4;
  const float4* H4 = (const float4*)hsv;
  float acc[CNUM][4] = {};
  for (int i = 0; i < MFD / 4 / 64; ++i) {
    int k4 = lane + i * 64;
    float4 w9v[4];
#pragma unroll
    for (int o = 0; o < 4; ++o)
      w9v[o] = *((const float4*)(W9 + (size_t)(o0 + o) * MFD) + k4);
#pragma unroll
    for (int c = 0; c < CNUM; ++c) {
      float4 hv = H4[(size_t)c * (MFD / 4) + k4];
#pragma unroll
      for (int o = 0; o < 4; ++o) acc[c][o] = dot4acc(hv, w9v[o], acc[c][o]);
    }
  }
#pragma unroll
  for (int c = 0; c < CNUM; ++c)
#pragma unroll
    for (int o = 0; o < 4; ++o)
#pragma unroll
      for (int s = 32; s; s >>= 1) acc[c][o] += __shfl_xor(acc[c][o], s);
  if (lane == 0) {
#pragma unroll
    for (int c = 0; c < CNUM; ++c) {
      bool ne = counts[c] > 0;
#pragma unroll
      for (int o = 0; o < 4; ++o) {
        int oo = o0 + o;
        float v = tanhf(acc[c][o] + b9[oo]);
        labels[(size_t)c * MFD + oo] = ne ? v : labinit[(size_t)c * MFD + oo];
      }
    }
  }
}

// ---------- row L2 norms ----------
__global__ __launch_bounds__(256) void rownorm(const float* __restrict__ X,
                                               float* __restrict__ out, int ncols) {
  const int b = blockIdx.x, t = threadIdx.x;
  const float4* X4 = (const float4*)(X + (size_t)b * ncols);
  float ss = 0.f;
  for (int i = t; i < ncols / 4; i += 256) {
    float4 v = X4[i];
    ss = dot4acc(v, v, ss);
  }
#pragma unroll
  for (int s = 32; s; s >>= 1) ss += __shfl_xor(ss, s);
  __shared__ float red[4];
  const int lane = t & 63, wid = t >> 6;
  if (lane == 0) red[wid] = ss;
  __syncthreads();
  if (t == 0) out[b] = sqrtf(red[0] + red[1] + red[2] + red[3]);
}

// ---------- outs[b,c] ----------
__global__ __launch_bounds__(256) void outs_kernel(const float* __restrict__ outb,
                                                   const float* __restrict__ labels,
                                                   const float* __restrict__ no,
                                                   const float* __restrict__ nl,
                                                   float* __restrict__ dout) {
  const int b = blockIdx.x, t = threadIdx.x;
  const float4* O4 = (const float4*)(outb + (size_t)b * MFD);
  const float4* L4 = (const float4*)labels;
  float acc[CNUM] = {};
  for (int i = t; i < MFD / 4; i += 256) {
    float4 ov = O4[i];
#pragma unroll
    for (int c = 0; c < CNUM; ++c)
      acc[c] = dot4acc(ov, L4[(size_t)c * (MFD / 4) + i], acc[c]);
  }
#pragma unroll
  for (int c = 0; c < CNUM; ++c)
#pragma unroll
    for (int s = 32; s; s >>= 1) acc[c] += __shfl_xor(acc[c], s);
  __shared__ float red[4][CNUM];
  const int lane = t & 63, wid = t >> 6;
  if (lane == 0) {
#pragma unroll
    for (int c = 0; c < CNUM; ++c) red[wid][c] = acc[c];
  }
  __syncthreads();
  if (t < CNUM) {
    float v = red[0][t] + red[1][t] + red[2][t] + red[3][t];
    float d = fmaxf(no[b] * nl[t], 1e-8f);
    dout[(size_t)b * CNUM + t] = v / d;
  }
}

// ---------- ls rows ----------
__global__ __launch_bounds__(256) void ls_kernel(const float* __restrict__ labels,
                                                 const float* __restrict__ W5,
                                                 const float* __restrict__ b5,
                                                 float* __restrict__ dout) {
  const int c1 = blockIdx.x, t = threadIdx.x;
  __shared__ float lrow[MFD];
  for (int i = t; i < MFD; i += 256) lrow[i] = labels[(size_t)c1 * MFD + i];
  __syncthreads();
  const int lane = t & 63, wid = t >> 6;
  for (int c2 = wid; c2 < CNUM; c2 += 4) {
    const float4* w = (const float4*)(W5 + (size_t)c2 * MFD);
    float acc = 0.f;
    for (int i = lane; i < MFD / 4; i += 64)
      acc = dot4acc(*(const float4*)&lrow[i * 4], w[i], acc);
#pragma unroll
    for (int s = 32; s; s >>= 1) acc += __shfl_xor(acc, s);
    if (lane == 0)
      dout[(size_t)(BATCH + c1) * CNUM + c2] = tanhf(acc + b5[c2]);
  }
}

extern "C" void kernel_launch(void* const* d_in, const int* in_sizes, int n_in,
                              void* d_out, int out_size, void* d_ws, size_t ws_size,
                              hipStream_t stream) {
  const float* x    = (const float*)d_in[0];
  const int*   lab  = (const int*)d_in[1];
  const float* W1 = (const float*)d_in[2];  const float* b1 = (const float*)d_in[3];
  const float* W2 = (const float*)d_in[4];  const float* b2 = (const float*)d_in[5];
  const float* W3 = (const float*)d_in[6];  const float* b3 = (const float*)d_in[7];
  const float* W4 = (const float*)d_in[8];  const float* b4 = (const float*)d_in[9];
  const float* W5 = (const float*)d_in[10]; const float* b5 = (const float*)d_in[11];
  const float* W7 = (const float*)d_in[12]; const float* b7 = (const float*)d_in[13];
  const float* W8 = (const float*)d_in[14]; const float* b8 = (const float*)d_in[15];
  const float* W9 = (const float*)d_in[16]; const float* b9 = (const float*)d_in[17];
  const float* hs_init  = (const float*)d_in[18];
  const float* lab_init = (const float*)d_in[19];
  float* out = (float*)d_out;

  char* base = (char*)d_ws;
  size_t off = 0;
  auto alloc = [&](size_t bytes) { char* p = base + off; off += (bytes + 255) & ~(size_t)255; return p; };

  unsigned short* xb  = (unsigned short*)alloc((size_t)BATCH * FDIM * 2);
  unsigned short* h1b = (unsigned short*)alloc((size_t)BATCH * FDIM * 2);
  unsigned short* h2b = (unsigned short*)alloc((size_t)BATCH * FDIM * 2);
  unsigned short* W1b = (unsigned short*)alloc((size_t)FDIM * FDIM * 2);
  unsigned short* W2b = (unsigned short*)alloc((size_t)FDIM * FDIM * 2);
  unsigned short* W3b = (unsigned short*)alloc((size_t)MFD * FDIM * 2);
  unsigned short* W4b = (unsigned short*)alloc((size_t)MFD * FDIM * 2);
  float* label0 = (float*)alloc((size_t)BATCH * MFD * 4);
  float* outb   = (float*)alloc((size_t)BATCH * MFD * 4);
  float* S      = (float*)alloc((size_t)CNUM * SMAX * SMAX * 4);
  float* wsum   = (float*)alloc((size_t)CNUM * SMAX * 4);
  float* attn   = (float*)alloc((size_t)CNUM * MFD * 4);
  float* hsbuf  = (float*)alloc((size_t)CNUM * MFD * 4);
  float* labels = (float*)alloc((size_t)CNUM * MFD * 4);
  float* no     = (float*)alloc((size_t)BATCH * 4);
  float* nl     = (float*)alloc(64 * 4);
  int* idx      = (int*)alloc((size_t)CNUM * BATCH * 4);
  int* counts   = (int*)alloc(64 * 4);

  // --- fp32 -> bf16 conversions ---
  cvt_bf16<<<(BATCH * FDIM / 4 + 255) / 256, 256, 0, stream>>>(x,  xb,  BATCH * FDIM / 4);
  cvt_bf16<<<(FDIM * FDIM / 4 + 255) / 256, 256, 0, stream>>>(W1, W1b, FDIM * FDIM / 4);
  cvt_bf16<<<(FDIM * FDIM / 4 + 255) / 256, 256, 0, stream>>>(W2, W2b, FDIM * FDIM / 4);
  cvt_bf16<<<(MFD * FDIM / 4 + 255) / 256, 256, 0, stream>>>(W3, W3b, MFD * FDIM / 4);
  cvt_bf16<<<(MFD * FDIM / 4 + 255) / 256, 256, 0, stream>>>(W4, W4b, MFD * FDIM / 4);

  // --- MLP via bf16 MFMA ---
  mfma_gemm<1, 1><<<dim3(FDIM / 128, BATCH / 128), 256, 0, stream>>>(xb,  W1b, b1, nullptr, h1b, BATCH, FDIM, FDIM);
  mfma_gemm<1, 1><<<dim3(FDIM / 128, BATCH / 128), 256, 0, stream>>>(h1b, W2b, b2, nullptr, h2b, BATCH, FDIM, FDIM);
  mfma_gemm<2, 0><<<dim3(MFD / 128, BATCH / 128), 256, 0, stream>>>(h2b, W3b, b3, label0, nullptr, BATCH, MFD, FDIM);
  mfma_gemm<2, 0><<<dim3(MFD / 128, BATCH / 128), 256, 0, stream>>>(h2b, W4b, b4, outb,   nullptr, BATCH, MFD, FDIM);

  // --- attention path (fp32) ---
  build_idx<<<1, 256, 0, stream>>>(lab, idx, counts);
  hipMemsetAsync(S, 0, (size_t)CNUM * SMAX * SMAX * 4, stream);
  gram_splitk<<<dim3(SMAX / 32, SMAX / 32, CNUM * KSPLIT), 256, 0, stream>>>(label0, idx, counts, S);
  softmax_w<<<CNUM, 256, 0, stream>>>(S, counts, wsum);
  attn_combine<<<dim3(MFD / 256, CNUM), 256, 0, stream>>>(label0, idx, counts, wsum, attn);
  skinny_hs<<<MFD / 16, 256, 0, stream>>>(attn, hs_init, W7, b7, W8, b8, counts, hsbuf);
  skinny_lab<<<MFD / 16, 256, 0, stream>>>(hsbuf, W9, b9, counts, lab_init, labels);
  rownorm<<<BATCH, 256, 0, stream>>>(outb, no, MFD);
  rownorm<<<CNUM, 256, 0, stream>>>(labels, nl, MFD);
  outs_kernel<<<BATCH, 256, 0, stream>>>(outb, labels, no, nl, out);
  ls_kernel<<<CNUM, 256, 0, stream>>>(labels, W5, b5, out);
}

// Round 5
// 601.208 us; speedup vs baseline: 2.0594x; 1.2999x over previous
//
#include <hip/hip_runtime.h>
#include <hip/hip_bf16.h>
#include <math.h>

#define FDIM 512
#define MFD  4096
#define CNUM 20
#define BATCH 2048
#define SMAX 256
#define GKS  16    // gram k-split: slice = MFD/GKS = 256
#define GBK  64    // gram k-step

typedef __attribute__((ext_vector_type(8))) short bf16x8;
typedef __attribute__((ext_vector_type(4))) float f32x4;

__device__ inline unsigned short f2bf1(float f) {
  union { float f; unsigned u; } a; a.f = f;
  unsigned r = a.u + 0x7fffu + ((a.u >> 16) & 1u);   // RNE
  return (unsigned short)(r >> 16);
}
__device__ inline float bf2f(unsigned short u) {
  union { unsigned u; float f; } a; a.u = ((unsigned)u) << 16; return a.f;
}
__device__ inline float fast_tanh(float x) {
  float cx = fminf(fmaxf(x, -15.f), 15.f);
  float e = __expf(2.f * cx);
  return (e - 1.f) / (e + 1.f);
}
__device__ inline float dot4acc(float4 a, float4 b, float acc) {
  acc = fmaf(a.x, b.x, acc); acc = fmaf(a.y, b.y, acc);
  acc = fmaf(a.z, b.z, acc); acc = fmaf(a.w, b.w, acc);
  return acc;
}
__device__ inline void gload_lds16(const void* g, void* l) {
  __builtin_amdgcn_global_load_lds(
      (const __attribute__((address_space(1))) unsigned int*)g,
      (__attribute__((address_space(3))) unsigned int*)l, 16, 0, 0);
}

// ---------------- fp32 -> bf16 conversion ----------------
__global__ __launch_bounds__(256) void cvt_bf16(const float* __restrict__ in,
                                                unsigned short* __restrict__ out, int n4) {
  int i = blockIdx.x * 256 + threadIdx.x;
  if (i >= n4) return;
  float4 v = ((const float4*)in)[i];
  ((ushort4*)out)[i] = make_ushort4(f2bf1(v.x), f2bf1(v.y), f2bf1(v.z), f2bf1(v.w));
}

// ---------------- bf16 MFMA GEMM: C = act(A @ B^T + bias) ----------------
// 128x128 tile, BK=32, 4 waves. XOR-swizzled 16B LDS slots (src+read, same involution).
// ACT: 0=none 1=relu 2=tanh.  OUTBF: 1 -> bf16 out (Cb), 0 -> fp32 out (Cf).
template<int ACT, int OUTBF>
__global__ __launch_bounds__(256) void mfma_gemm(const unsigned short* __restrict__ A,
                                                 const unsigned short* __restrict__ B,
                                                 const float* __restrict__ bias,
                                                 float* __restrict__ Cf,
                                                 unsigned short* __restrict__ Cb,
                                                 int M, int N, int K) {
  __shared__ __align__(16) char lds[16384];
  const int t = threadIdx.x, lane = t & 63, w = t >> 6;
  const int wr = w >> 1, wc = w & 1;
  const int m0 = blockIdx.y * 128, n0 = blockIdx.x * 128;

  f32x4 acc[4][4];
#pragma unroll
  for (int m = 0; m < 4; ++m)
#pragma unroll
    for (int n = 0; n < 4; ++n) acc[m][n] = (f32x4){0.f, 0.f, 0.f, 0.f};

  int rS[2], qS[2];
#pragma unroll
  for (int i = 0; i < 2; ++i) {
    int t16 = (w * 2 + i) * 64 + lane;
    rS[i] = t16 >> 2;
    qS[i] = (t16 & 3) ^ ((rS[i] >> 1) & 3);
  }

  for (int k0 = 0; k0 < K; k0 += 32) {
#pragma unroll
    for (int i = 0; i < 2; ++i) {
      gload_lds16(A + (size_t)(m0 + rS[i]) * K + k0 + qS[i] * 8,
                  lds + (w * 2 + i) * 1024);
      gload_lds16(B + (size_t)(n0 + rS[i]) * K + k0 + qS[i] * 8,
                  lds + 8192 + (w * 2 + i) * 1024);
    }
    __syncthreads();

    bf16x8 af[4], bfr[4];
    const int kq = lane >> 4, l15 = lane & 15;
#pragma unroll
    for (int m = 0; m < 4; ++m) {
      int ra = wr * 64 + m * 16 + l15;
      af[m] = *(const bf16x8*)(lds + ra * 64 + ((kq ^ ((ra >> 1) & 3)) << 4));
      int rb = wc * 64 + m * 16 + l15;
      bfr[m] = *(const bf16x8*)(lds + 8192 + rb * 64 + ((kq ^ ((rb >> 1) & 3)) << 4));
    }
#pragma unroll
    for (int m = 0; m < 4; ++m)
#pragma unroll
      for (int n = 0; n < 4; ++n)
        acc[m][n] = __builtin_amdgcn_mfma_f32_16x16x32_bf16(af[m], bfr[n], acc[m][n], 0, 0, 0);
    __syncthreads();
  }

  // C/D layout: col = lane&15, row = (lane>>4)*4 + j  [m89-verified]
#pragma unroll
  for (int n = 0; n < 4; ++n) {
    int col = n0 + wc * 64 + n * 16 + (lane & 15);
    float bv = bias[col];
#pragma unroll
    for (int m = 0; m < 4; ++m) {
      int rbase = m0 + wr * 64 + m * 16 + ((lane >> 4) << 2);
#pragma unroll
      for (int j = 0; j < 4; ++j) {
        float v = acc[m][n][j] + bv;
        if (ACT == 1) v = fmaxf(v, 0.f);
        if (ACT == 2) v = fast_tanh(v);
        if (OUTBF) Cb[(size_t)(rbase + j) * N + col] = f2bf1(v);
        else       Cf[(size_t)(rbase + j) * N + col] = v;
      }
    }
  }
}

// ---------------- per-class index lists ----------------
__global__ void build_idx(const int* __restrict__ label, int* __restrict__ idx,
                          int* __restrict__ counts) {
  __shared__ int cnt[CNUM];
  int t = threadIdx.x;
  if (t < CNUM) cnt[t] = 0;
  __syncthreads();
  for (int b = t; b < BATCH; b += 256) {
    int c = label[b];
    int p = atomicAdd(&cnt[c], 1);
    idx[c * BATCH + p] = b;
  }
  __syncthreads();
  if (t < CNUM) counts[t] = cnt[t];
}

// -------- per-class gram via MFMA: S_c += G_c(bf16) @ G_c^T, split-K, atomics --------
// grid (GKS, 4 tile-pairs, CNUM), 256 thr. LDS: A-tile [128][64]bf16 16KB (+B 16KB).
// Swizzle: physical slot p holds logical k-chunk p^(row&7); staged via swizzled SOURCE.
__global__ __launch_bounds__(256) void gram_mfma(const unsigned short* __restrict__ Gb,
                                                 const int* __restrict__ idx,
                                                 const int* __restrict__ counts,
                                                 float* __restrict__ S) {
  const int c = blockIdx.z, n = counts[c];
  const int tp = blockIdx.y, ti = tp >> 1, tj = tp & 1;
  const int i0 = ti * 128, j0 = tj * 128;
  if (i0 >= n || j0 >= n) return;
  const int* idc = idx + c * BATCH;
  __shared__ __align__(16) char lds[32768];
  const bool same = (ti == tj);
  char* ldsB = same ? lds : (lds + 16384);

  const int t = threadIdx.x, lane = t & 63, w = t >> 6;
  size_t offA[4], offB[4];
#pragma unroll
  for (int q = 0; q < 4; ++q) {
    int t16 = q * 256 + t;
    int r = t16 >> 3, p = t16 & 7;
    int ch = p ^ (r & 7);
    int ia = i0 + r, jb = j0 + r;
    offA[q] = (size_t)idc[ia < n ? ia : 0] * MFD + ch * 8;
    offB[q] = (size_t)idc[jb < n ? jb : 0] * MFD + ch * 8;
  }
  const int kbeg = blockIdx.x * (MFD / GKS);

  f32x4 acc[2][8];
#pragma unroll
  for (int fi = 0; fi < 2; ++fi)
#pragma unroll
    for (int fj = 0; fj < 8; ++fj) acc[fi][fj] = (f32x4){0.f, 0.f, 0.f, 0.f};

  const int l15 = lane & 15, kq = lane >> 4;
  for (int k0 = kbeg; k0 < kbeg + MFD / GKS; k0 += GBK) {
#pragma unroll
    for (int q = 0; q < 4; ++q) {
      gload_lds16(Gb + offA[q] + k0, lds + q * 4096 + w * 1024 + (lane << 4));
      if (!same)
        gload_lds16(Gb + offB[q] + k0, ldsB + q * 4096 + w * 1024 + (lane << 4));
    }
    __syncthreads();
#pragma unroll
    for (int kk = 0; kk < 2; ++kk) {
      bf16x8 a[2], b[8];
#pragma unroll
      for (int fi = 0; fi < 2; ++fi) {
        int r = w * 32 + fi * 16 + l15;
        int sl = (kk * 4 + kq) ^ (r & 7);
        a[fi] = *(const bf16x8*)(lds + r * 128 + sl * 16);
      }
#pragma unroll
      for (int fj = 0; fj < 8; ++fj) {
        int r = fj * 16 + l15;
        int sl = (kk * 4 + kq) ^ (r & 7);
        b[fj] = *(const bf16x8*)(ldsB + r * 128 + sl * 16);
      }
#pragma unroll
      for (int fi = 0; fi < 2; ++fi)
#pragma unroll
        for (int fj = 0; fj < 8; ++fj)
          acc[fi][fj] = __builtin_amdgcn_mfma_f32_16x16x32_bf16(a[fi], b[fj], acc[fi][fj], 0, 0, 0);
    }
    __syncthreads();
  }

  float* Sc = S + (size_t)c * SMAX * SMAX;
#pragma unroll
  for (int fi = 0; fi < 2; ++fi) {
    int ibase = i0 + w * 32 + fi * 16 + (lane >> 4) * 4;
#pragma unroll
    for (int fj = 0; fj < 8; ++fj) {
      int j = j0 + fj * 16 + l15;
#pragma unroll
      for (int jj = 0; jj < 4; ++jj)
        atomicAdd(&Sc[(size_t)(ibase + jj) * SMAX + j], acc[fi][fj][jj]);
    }
  }
}

// ---------- row softmax of S, column-weight accumulate (W pre-zeroed) ----------
// grid (8, CNUM): block handles rows i = bx*4+wid (+32 stride); atomic merge into W.
__global__ __launch_bounds__(256) void softmax_w2(const float* __restrict__ S,
                                                  const int* __restrict__ counts,
                                                  float* __restrict__ W) {
  const int c = blockIdx.y;
  const int n = counts[c];
  __shared__ float wacc[4][SMAX];
  const int t = threadIdx.x, lane = t & 63, wid = t >> 6;
  for (int j = t; j < 4 * SMAX; j += 256) (&wacc[0][0])[j] = 0.f;
  __syncthreads();
  const float* Sc = S + (size_t)c * SMAX * SMAX;
  for (int i = blockIdx.x * 4 + wid; i < n; i += 32) {
    const float* row = Sc + (size_t)i * SMAX;
    float v[4];
    float m = -INFINITY;
#pragma unroll
    for (int q = 0; q < 4; ++q) {
      int j = lane + q * 64;
      v[q] = (j < n) ? row[j] : -INFINITY;
      m = fmaxf(m, v[q]);
    }
#pragma unroll
    for (int s = 32; s; s >>= 1) m = fmaxf(m, __shfl_xor(m, s));
    float e[4], sum = 0.f;
#pragma unroll
    for (int q = 0; q < 4; ++q) {
      int j = lane + q * 64;
      e[q] = (j < n) ? expf(v[q] - m) : 0.f;
      sum += e[q];
    }
#pragma unroll
    for (int s = 32; s; s >>= 1) sum += __shfl_xor(sum, s);
    float inv = 1.f / sum;
#pragma unroll
    for (int q = 0; q < 4; ++q) {
      int j = lane + q * 64;
      if (j < n) wacc[wid][j] += e[q] * inv;
    }
  }
  __syncthreads();
  for (int j = t; j < SMAX; j += 256) {
    float v = wacc[0][j] + wacc[1][j] + wacc[2][j] + wacc[3][j];
    if (v != 0.f) atomicAdd(&W[c * SMAX + j], v);
  }
}

// ---------- attn[c,:] = (1/n) * sum_j w_j * label0b[idc[j], :]  (bf16 reads) ----------
__global__ __launch_bounds__(256) void attn_combine2(const unsigned short* __restrict__ Gb,
                                                     const int* __restrict__ idx,
                                                     const int* __restrict__ counts,
                                                     const float* __restrict__ W,
                                                     float* __restrict__ attn) {
  const int c = blockIdx.y, n = counts[c];
  const int col2 = blockIdx.x * 256 + threadIdx.x;   // ushort2 index
  const int* idc = idx + c * BATCH;
  const float* Wc = W + c * SMAX;
  float a0 = 0.f, a1 = 0.f;
#pragma unroll 4
  for (int j = 0; j < n; ++j) {
    float wj = Wc[j];
    ushort2 g = ((const ushort2*)(Gb + (size_t)idc[j] * MFD))[col2];
    a0 = fmaf(wj, bf2f(g.x), a0);
    a1 = fmaf(wj, bf2f(g.y), a1);
  }
  float inv = (n > 0) ? 1.f / (float)n : 0.f;
  ((float2*)attn)[(size_t)c * (MFD / 2) + col2] = make_float2(a0 * inv, a1 * inv);
}

// ---------- hs = select(sigmoid(attn@W7^T + b7 + hs_init@W8^T + b8), hs_init) ----------
__global__ __launch_bounds__(256) void skinny_hs(const float* __restrict__ attn,
                                                 const float* __restrict__ hsin,
                                                 const float* __restrict__ W7,
                                                 const float* __restrict__ b7,
                                                 const float* __restrict__ W8,
                                                 const float* __restrict__ b8,
                                                 const int* __restrict__ counts,
                                                 float* __restrict__ hs) {
  const int t = threadIdx.x, lane = t & 63, wid = t >> 6;
  const int o0 = blockIdx.x * 16 + wid * 4;
  const float4* A4 = (const float4*)attn;
  const float4* H4 = (const float4*)hsin;
  float acc[CNUM][4] = {};
  for (int i = 0; i < MFD / 4 / 64; ++i) {
    int k4 = lane + i * 64;
    float4 w7v[4], w8v[4];
#pragma unroll
    for (int o = 0; o < 4; ++o) {
      w7v[o] = *((const float4*)(W7 + (size_t)(o0 + o) * MFD) + k4);
      w8v[o] = *((const float4*)(W8 + (size_t)(o0 + o) * MFD) + k4);
    }
#pragma unroll
    for (int c = 0; c < CNUM; ++c) {
      float4 av = A4[(size_t)c * (MFD / 4) + k4];
      float4 hv = H4[(size_t)c * (MFD / 4) + k4];
#pragma unroll
      for (int o = 0; o < 4; ++o)
        acc[c][o] = dot4acc(hv, w8v[o], dot4acc(av, w7v[o], acc[c][o]));
    }
  }
#pragma unroll
  for (int c = 0; c < CNUM; ++c)
#pragma unroll
    for (int o = 0; o < 4; ++o)
#pragma unroll
      for (int s = 32; s; s >>= 1) acc[c][o] += __shfl_xor(acc[c][o], s);
  if (lane == 0) {
#pragma unroll
    for (int c = 0; c < CNUM; ++c) {
      bool ne = counts[c] > 0;
#pragma unroll
      for (int o = 0; o < 4; ++o) {
        int oo = o0 + o;
        float v = acc[c][o] + b7[oo] + b8[oo];
        v = 1.f / (1.f + expf(-v));
        hs[(size_t)c * MFD + oo] = ne ? v : hsin[(size_t)c * MFD + oo];
      }
    }
  }
}

// ---------- labels = select(tanh(hs@W9^T + b9), labels_init) ----------
__global__ __launch_bounds__(256) void skinny_lab(const float* __restrict__ hsv,
                                                  const float* __restrict__ W9,
                                                  const float* __restrict__ b9,
                                                  const int* __restrict__ counts,
                                                  const float* __restrict__ labinit,
                                                  float* __restrict__ labels) {
  const int t = threadIdx.x, lane = t & 63, wid = t >> 6;
  const int o0 = blockIdx.x * 16 + wid * 4;
  const float4* H4 = (const float4*)hsv;
  float acc[CNUM][4] = {};
  for (int i = 0; i < MFD / 4 / 64; ++i) {
    int k4 = lane + i * 64;
    float4 w9v[4];
#pragma unroll
    for (int o = 0; o < 4; ++o)
      w9v[o] = *((const float4*)(W9 + (size_t)(o0 + o) * MFD) + k4);
#pragma unroll
    for (int c = 0; c < CNUM; ++c) {
      float4 hv = H4[(size_t)c * (MFD / 4) + k4];
#pragma unroll
      for (int o = 0; o < 4; ++o) acc[c][o] = dot4acc(hv, w9v[o], acc[c][o]);
    }
  }
#pragma unroll
  for (int c = 0; c < CNUM; ++c)
#pragma unroll
    for (int o = 0; o < 4; ++o)
#pragma unroll
      for (int s = 32; s; s >>= 1) acc[c][o] += __shfl_xor(acc[c][o], s);
  if (lane == 0) {
#pragma unroll
    for (int c = 0; c < CNUM; ++c) {
      bool ne = counts[c] > 0;
#pragma unroll
      for (int o = 0; o < 4; ++o) {
        int oo = o0 + o;
        float v = tanhf(acc[c][o] + b9[oo]);
        labels[(size_t)c * MFD + oo] = ne ? v : labinit[(size_t)c * MFD + oo];
      }
    }
  }
}

// ---------- row L2 norms ----------
__global__ __launch_bounds__(256) void rownorm(const float* __restrict__ X,
                                               float* __restrict__ out, int ncols) {
  const int b = blockIdx.x, t = threadIdx.x;
  const float4* X4 = (const float4*)(X + (size_t)b * ncols);
  float ss = 0.f;
  for (int i = t; i < ncols / 4; i += 256) {
    float4 v = X4[i];
    ss = dot4acc(v, v, ss);
  }
#pragma unroll
  for (int s = 32; s; s >>= 1) ss += __shfl_xor(ss, s);
  __shared__ float red[4];
  const int lane = t & 63, wid = t >> 6;
  if (lane == 0) red[wid] = ss;
  __syncthreads();
  if (t == 0) out[b] = sqrtf(red[0] + red[1] + red[2] + red[3]);
}

// ---------- outs[b,c] ----------
__global__ __launch_bounds__(256) void outs_kernel(const float* __restrict__ outb,
                                                   const float* __restrict__ labels,
                                                   const float* __restrict__ no,
                                                   const float* __restrict__ nl,
                                                   float* __restrict__ dout) {
  const int b = blockIdx.x, t = threadIdx.x;
  const float4* O4 = (const float4*)(outb + (size_t)b * MFD);
  const float4* L4 = (const float4*)labels;
  float acc[CNUM] = {};
  for (int i = t; i < MFD / 4; i += 256) {
    float4 ov = O4[i];
#pragma unroll
    for (int c = 0; c < CNUM; ++c)
      acc[c] = dot4acc(ov, L4[(size_t)c * (MFD / 4) + i], acc[c]);
  }
#pragma unroll
  for (int c = 0; c < CNUM; ++c)
#pragma unroll
    for (int s = 32; s; s >>= 1) acc[c] += __shfl_xor(acc[c], s);
  __shared__ float red[4][CNUM];
  const int lane = t & 63, wid = t >> 6;
  if (lane == 0) {
#pragma unroll
    for (int c = 0; c < CNUM; ++c) red[wid][c] = acc[c];
  }
  __syncthreads();
  if (t < CNUM) {
    float v = red[0][t] + red[1][t] + red[2][t] + red[3][t];
    float d = fmaxf(no[b] * nl[t], 1e-8f);
    dout[(size_t)b * CNUM + t] = v / d;
  }
}

// ---------- ls rows ----------
__global__ __launch_bounds__(256) void ls_kernel(const float* __restrict__ labels,
                                                 const float* __restrict__ W5,
                                                 const float* __restrict__ b5,
                                                 float* __restrict__ dout) {
  const int c1 = blockIdx.x, t = threadIdx.x;
  __shared__ float lrow[MFD];
  for (int i = t; i < MFD; i += 256) lrow[i] = labels[(size_t)c1 * MFD + i];
  __syncthreads();
  const int lane = t & 63, wid = t >> 6;
  for (int c2 = wid; c2 < CNUM; c2 += 4) {
    const float4* w = (const float4*)(W5 + (size_t)c2 * MFD);
    float acc = 0.f;
    for (int i = lane; i < MFD / 4; i += 64)
      acc = dot4acc(*(const float4*)&lrow[i * 4], w[i], acc);
#pragma unroll
    for (int s = 32; s; s >>= 1) acc += __shfl_xor(acc, s);
    if (lane == 0)
      dout[(size_t)(BATCH + c1) * CNUM + c2] = tanhf(acc + b5[c2]);
  }
}

extern "C" void kernel_launch(void* const* d_in, const int* in_sizes, int n_in,
                              void* d_out, int out_size, void* d_ws, size_t ws_size,
                              hipStream_t stream) {
  const float* x    = (const float*)d_in[0];
  const int*   lab  = (const int*)d_in[1];
  const float* W1 = (const float*)d_in[2];  const float* b1 = (const float*)d_in[3];
  const float* W2 = (const float*)d_in[4];  const float* b2 = (const float*)d_in[5];
  const float* W3 = (const float*)d_in[6];  const float* b3 = (const float*)d_in[7];
  const float* W4 = (const float*)d_in[8];  const float* b4 = (const float*)d_in[9];
  const float* W5 = (const float*)d_in[10]; const float* b5 = (const float*)d_in[11];
  const float* W7 = (const float*)d_in[12]; const float* b7 = (const float*)d_in[13];
  const float* W8 = (const float*)d_in[14]; const float* b8 = (const float*)d_in[15];
  const float* W9 = (const float*)d_in[16]; const float* b9 = (const float*)d_in[17];
  const float* hs_init  = (const float*)d_in[18];
  const float* lab_init = (const float*)d_in[19];
  float* out = (float*)d_out;

  char* base = (char*)d_ws;
  size_t off = 0;
  auto alloc = [&](size_t bytes) { char* p = base + off; off += (bytes + 255) & ~(size_t)255; return p; };

  unsigned short* xb  = (unsigned short*)alloc((size_t)BATCH * FDIM * 2);
  unsigned short* h1b = (unsigned short*)alloc((size_t)BATCH * FDIM * 2);
  unsigned short* h2b = (unsigned short*)alloc((size_t)BATCH * FDIM * 2);
  unsigned short* W1b = (unsigned short*)alloc((size_t)FDIM * FDIM * 2);
  unsigned short* W2b = (unsigned short*)alloc((size_t)FDIM * FDIM * 2);
  unsigned short* W3b = (unsigned short*)alloc((size_t)MFD * FDIM * 2);
  unsigned short* W4b = (unsigned short*)alloc((size_t)MFD * FDIM * 2);
  unsigned short* label0b = (unsigned short*)alloc((size_t)BATCH * MFD * 2);
  float* outb   = (float*)alloc((size_t)BATCH * MFD * 4);
  float* S      = (float*)alloc((size_t)CNUM * SMAX * SMAX * 4);   // contiguous with wsum
  float* wsum   = (float*)alloc((size_t)CNUM * SMAX * 4);
  float* attn   = (float*)alloc((size_t)CNUM * MFD * 4);
  float* hsbuf  = (float*)alloc((size_t)CNUM * MFD * 4);
  float* labels = (float*)alloc((size_t)CNUM * MFD * 4);
  float* no     = (float*)alloc((size_t)BATCH * 4);
  float* nl     = (float*)alloc(64 * 4);
  int* idx      = (int*)alloc((size_t)CNUM * BATCH * 4);
  int* counts   = (int*)alloc(64 * 4);

  // --- fp32 -> bf16 conversions ---
  cvt_bf16<<<(BATCH * FDIM / 4 + 255) / 256, 256, 0, stream>>>(x,  xb,  BATCH * FDIM / 4);
  cvt_bf16<<<(FDIM * FDIM / 4 + 255) / 256, 256, 0, stream>>>(W1, W1b, FDIM * FDIM / 4);
  cvt_bf16<<<(FDIM * FDIM / 4 + 255) / 256, 256, 0, stream>>>(W2, W2b, FDIM * FDIM / 4);
  cvt_bf16<<<(MFD * FDIM / 4 + 255) / 256, 256, 0, stream>>>(W3, W3b, MFD * FDIM / 4);
  cvt_bf16<<<(MFD * FDIM / 4 + 255) / 256, 256, 0, stream>>>(W4, W4b, MFD * FDIM / 4);

  // --- MLP via bf16 MFMA ---
  mfma_gemm<1, 1><<<dim3(FDIM / 128, BATCH / 128), 256, 0, stream>>>(xb,  W1b, b1, nullptr, h1b, BATCH, FDIM, FDIM);
  mfma_gemm<1, 1><<<dim3(FDIM / 128, BATCH / 128), 256, 0, stream>>>(h1b, W2b, b2, nullptr, h2b, BATCH, FDIM, FDIM);
  mfma_gemm<2, 1><<<dim3(MFD / 128, BATCH / 128), 256, 0, stream>>>(h2b, W3b, b3, nullptr, label0b, BATCH, MFD, FDIM);
  mfma_gemm<2, 0><<<dim3(MFD / 128, BATCH / 128), 256, 0, stream>>>(h2b, W4b, b4, outb,   nullptr,  BATCH, MFD, FDIM);

  // --- attention path ---
  build_idx<<<1, 256, 0, stream>>>(lab, idx, counts);
  hipMemsetAsync(S, 0, (size_t)CNUM * SMAX * SMAX * 4 + (size_t)CNUM * SMAX * 4, stream); // S + wsum
  gram_mfma<<<dim3(GKS, 4, CNUM), 256, 0, stream>>>(label0b, idx, counts, S);
  softmax_w2<<<dim3(8, CNUM), 256, 0, stream>>>(S, counts, wsum);
  attn_combine2<<<dim3(MFD / 512, CNUM), 256, 0, stream>>>(label0b, idx, counts, wsum, attn);
  skinny_hs<<<MFD / 16, 256, 0, stream>>>(attn, hs_init, W7, b7, W8, b8, counts, hsbuf);
  skinny_lab<<<MFD / 16, 256, 0, stream>>>(hsbuf, W9, b9, counts, lab_init, labels);
  rownorm<<<BATCH, 256, 0, stream>>>(outb, no, MFD);
  rownorm<<<CNUM, 256, 0, stream>>>(labels, nl, MFD);
  outs_kernel<<<BATCH, 256, 0, stream>>>(outb, labels, no, nl, out);
  ls_kernel<<<CNUM, 256, 0, stream>>>(labels, W5, b5, out);
}